// Round 2
// baseline (665.160 us; speedup 1.0000x reference)
//
#include <hip/hip_runtime.h>

typedef __attribute__((ext_vector_type(8))) short short8;
typedef __attribute__((ext_vector_type(4))) short short4v;
typedef __attribute__((ext_vector_type(4))) float float4v;

// ws layout (shorts unless noted):
//   [0      , 65536) : Wc1 = Wf[:, :128] @ Wa   bf16, B-frag-major: ((kc*8+nt)*64+lane)*8+j
//   [65536  , 73728) : Wc2 = Wf[:, 128:] @ Wt   bf16, ((hf*8+nt)*64+lane)*8+j
//   [73728  , 86016) : Whh bf16 frags            ((nt2*2+hf)*64+lane)*8+j, col=nt2*16+c
//   byte 172032      : bc[128] f32 = bf + Wf[:, :128]@ba + Wf[:, 128:]@bt
#define WC2_OFF 65536
#define WHH_OFF 73728
#define BC_BYTE_OFF 172032

static __device__ __forceinline__ unsigned short f2bf(float f) {
  unsigned int u = __float_as_uint(f);
  u = (u + 0x7fffu + ((u >> 16) & 1u)) >> 16;   // RNE
  return (unsigned short)u;
}

static __device__ __forceinline__ short8 pack8cvt(float4v a, float4v b) {
  unsigned int u0, u1, u2, u3;
  asm("v_cvt_pk_bf16_f32 %0, %1, %2" : "=v"(u0) : "v"(a.x), "v"(a.y));
  asm("v_cvt_pk_bf16_f32 %0, %1, %2" : "=v"(u1) : "v"(a.z), "v"(a.w));
  asm("v_cvt_pk_bf16_f32 %0, %1, %2" : "=v"(u2) : "v"(b.x), "v"(b.y));
  asm("v_cvt_pk_bf16_f32 %0, %1, %2" : "=v"(u3) : "v"(b.z), "v"(b.w));
  union { unsigned int u[4]; short8 s; } r;
  r.u[0] = u0; r.u[1] = u1; r.u[2] = u2; r.u[3] = u3;
  return r.s;
}

// sigmoid(x) ~ 0.5 + x*(0.25 + s1*x^2 + s2*x^4) on [-2.4,2.4]; gate preacts are |x|<~0.8
static __device__ __forceinline__ float sig_poly(float x) {
  x = fminf(2.4f, fmaxf(-2.4f, x));
  float x2 = x * x;
  float t = fmaf(0.0010218f, x2, -0.0191312f);
  t = fmaf(t, x2, 0.25f);
  return fmaf(x, t, 0.5f);
}
// tanh(x) ~ x*(1 + c1*x^2 + c2*x^4) on [-1.2,1.2]
static __device__ __forceinline__ float tanh_poly(float x) {
  x = fminf(1.2f, fmaxf(-1.2f, x));
  float x2 = x * x;
  float t = fmaf(0.0654f, x2, -0.3061f);
  t = fmaf(t, x2, 1.0f);
  return x * t;
}

#define MFMA16x16(a, b, c) __builtin_amdgcn_mfma_f32_16x16x32_bf16((a), (b), (c), 0, 0, 0)

// ---------------- setup: fold the affine tail + pre-pack all MFMA B-fragments ----------------
__global__ __launch_bounds__(256) void tie_setup(
    const float* __restrict__ Whh,
    const float* __restrict__ Wt, const float* __restrict__ bt,
    const float* __restrict__ Wa, const float* __restrict__ ba,
    const float* __restrict__ Wf, const float* __restrict__ bfv,
    short* __restrict__ wfrag, float* __restrict__ bc)
{
  int gid = blockIdx.x * 256 + (int)threadIdx.x;
  if (gid < 65536) {                       // Wc1[n][k], n<128, k<512
    int n = gid >> 9, k = gid & 511;
    const float* wfr = Wf + (long)n * 256;
    const float* wac = Wa + k;
    float s = 0.f;
    for (int j = 0; j < 128; ++j) s = fmaf(wfr[j], wac[(long)j * 512], s);
    int nt = n >> 4, cc = n & 15, kc = k >> 5, qq = (k >> 3) & 3, jj = k & 7;
    wfrag[(((kc * 8 + nt) * 64 + (qq * 16 + cc)) * 8) + jj] = (short)f2bf(s);
  } else if (gid < 73728) {                // Wc2[n][k], n<128, k<64
    int i = gid - 65536;
    int n = i >> 6, k = i & 63;
    const float* wfr = Wf + (long)n * 256 + 128;
    const float* wtc = Wt + k;
    float s = 0.f;
    for (int j = 0; j < 128; ++j) s = fmaf(wfr[j], wtc[(long)j * 64], s);
    int nt = n >> 4, cc = n & 15, hf = k >> 5, qq = (k >> 3) & 3, jj = k & 7;
    wfrag[WC2_OFF + (((hf * 8 + nt) * 64 + (qq * 16 + cc)) * 8) + jj] = (short)f2bf(s);
  } else if (gid < 86016) {                // Whh bf16 frag pack (identity copy into frag layout)
    int i = gid - 73728;
    int jj = i & 7, lane = (i >> 3) & 63, hf = (i >> 9) & 1, nt2 = i >> 10;
    int cc = lane & 15, qq = lane >> 4;
    float v = Whh[(long)(nt2 * 16 + cc) * 64 + hf * 32 + qq * 8 + jj];
    wfrag[WHH_OFF + i] = (short)f2bf(v);
  } else if (gid < 86016 + 128) {          // bc
    int n = gid - 86016;
    const float* wfr = Wf + (long)n * 256;
    float s = bfv[n];
    for (int j = 0; j < 128; ++j) s = fmaf(wfr[j], ba[j], fmaf(wfr[128 + j], bt[j], s));
    bc[n] = s;
  }
}

// ---------------- main ----------------
// Block = 256 threads (4 waves), 64 rows/block.
// GRU is DIM-SPLIT (wave wv owns h-dims [wv*16,+16) for all 64 rows); the emb@Wc1^T GEMM is
// ROW-split (wave wv owns rows [wv*16,+16)) and is FUSED into the 16 GRU steps: step s also
// processes emb k-chunk kc=s. HBM emb loads (issued one step ahead) hide under gate VALU;
// wfrag B-frags load in two halves of 4 so the second half's L2 latency hides under gates.
// After the loop: + h_last @ Wc2^T + bc, exact GELU, coalesced-ordered stores.
__global__ __launch_bounds__(256, 3) void tie_main(
    const float* __restrict__ emb, const float* __restrict__ cent,
    const float* __restrict__ Wih, const float* __restrict__ bih,
    const float* __restrict__ bhh,
    const short* __restrict__ wfrag, const float* __restrict__ bc,
    float* __restrict__ out)
{
  __shared__ __align__(16) short hb0[64][72];   // h ping (+8 pad: stride 144B -> conflict-free frag reads)
  __shared__ __align__(16) short hb1[64][72];   // h pong
  __shared__ __align__(16) float xs[64][36];    // centroid history [row][2*step], +4 pad

  const int tid = (int)threadIdx.x;
  const int lane = tid & 63;
  const int wv = tid >> 6;
  const int c = lane & 15;
  const int q = lane >> 4;
  const int dcol = wv * 16 + c;                 // this lane's h-dim in the GRU
  const int r0 = wv * 16;                       // this wave's output-row base
  const long rowblk = (long)blockIdx.x * 64;

  // ---- init: zero h ping, stage x into LDS ----
  {
    short8 z8 = {0, 0, 0, 0, 0, 0, 0, 0};
    short8* hp = (short8*)&hb0[0][0];
    for (int i = tid; i < 576; i += 256) hp[i] = z8;
    const float* cb = cent + rowblk * 32;
    int row = tid >> 2, col0 = (tid & 3) * 8;
    float4v v0 = *(const float4v*)(cb + tid * 8);
    float4v v1 = *(const float4v*)(cb + tid * 8 + 4);
    *(float4v*)&xs[row][col0] = v0;
    *(float4v*)&xs[row][col0 + 4] = v1;
  }

  // ---- per-lane scalar gate constants (dim = dcol) ----
  const int gr = dcol, gz = 64 + dcol, gn = 128 + dcol;
  const float accb_r = bih[gr] + bhh[gr];
  const float accb_z = bih[gz] + bhh[gz];
  const float accb_n = bhh[gn];                 // n-gate: r multiplies (hn + b_hh) only
  const float bxn = bih[gn];
  const float wr0 = Wih[2 * gr], wr1 = Wih[2 * gr + 1];
  const float wz0 = Wih[2 * gz], wz1 = Wih[2 * gz + 1];
  const float wn0 = Wih[2 * gn], wn1 = Wih[2 * gn + 1];

  // ---- Whh B-frags for this wave's 16 dims: 3 gates x 2 k-halves = 24 VGPR ----
  const short* whbase = wfrag + WHH_OFF;
  short8 whh_r0 = *(const short8*)(whbase + ((((0 * 4 + wv) * 2 + 0) * 64 + lane) * 8));
  short8 whh_r1 = *(const short8*)(whbase + ((((0 * 4 + wv) * 2 + 1) * 64 + lane) * 8));
  short8 whh_z0 = *(const short8*)(whbase + ((((1 * 4 + wv) * 2 + 0) * 64 + lane) * 8));
  short8 whh_z1 = *(const short8*)(whbase + ((((1 * 4 + wv) * 2 + 1) * 64 + lane) * 8));
  short8 whh_n0 = *(const short8*)(whbase + ((((2 * 4 + wv) * 2 + 0) * 64 + lane) * 8));
  short8 whh_n1 = *(const short8*)(whbase + ((((2 * 4 + wv) * 2 + 1) * 64 + lane) * 8));

  float hprev[4][4];
#pragma unroll
  for (int rt = 0; rt < 4; ++rt)
#pragma unroll
    for (int g = 0; g < 4; ++g) hprev[rt][g] = 0.0f;

  // ---- fused-output accumulators (bc bias folded in) + first emb fragment ----
  float4v acc[8];
#pragma unroll
  for (int nt = 0; nt < 8; ++nt) {
    float bv = bc[nt * 16 + c];
    acc[nt] = (float4v){bv, bv, bv, bv};
  }
  const float* erow = emb + (rowblk + r0 + c) * 512;   // emb A-frag row m = c
  float4v e0 = *(const float4v*)(erow + q * 8);
  float4v e1 = *(const float4v*)(erow + q * 8 + 4);

  __syncthreads();

  // One fused step: GRU step S (read HR, write HW) + emb k-chunk kc=S.
#define FUSED_STEP(S, HR, HW)                                                 \
  do {                                                                        \
    /* 1st half of Wc1 frags for this k-chunk */                              \
    short8 wb0_ = *(const short8*)(wfrag + ((((S) * 8 + 0) * 64 + lane) * 8));\
    short8 wb1_ = *(const short8*)(wfrag + ((((S) * 8 + 1) * 64 + lane) * 8));\
    short8 wb2_ = *(const short8*)(wfrag + ((((S) * 8 + 2) * 64 + lane) * 8));\
    short8 wb3_ = *(const short8*)(wfrag + ((((S) * 8 + 3) * 64 + lane) * 8));\
    float4v aR[4], aZ[4], aN[4];                                              \
    _Pragma("unroll")                                                         \
    for (int rt = 0; rt < 4; ++rt) {                                          \
      aR[rt] = (float4v){accb_r, accb_r, accb_r, accb_r};                     \
      aZ[rt] = (float4v){accb_z, accb_z, accb_z, accb_z};                     \
      aN[rt] = (float4v){accb_n, accb_n, accb_n, accb_n};                     \
    }                                                                         \
    _Pragma("unroll")                                                         \
    for (int rt = 0; rt < 4; ++rt) {                                          \
      short8 a0 = *(const short8*)&HR[rt * 16 + c][q * 8];                    \
      short8 a1 = *(const short8*)&HR[rt * 16 + c][32 + q * 8];               \
      aR[rt] = MFMA16x16(a0, whh_r0, aR[rt]);                                 \
      aR[rt] = MFMA16x16(a1, whh_r1, aR[rt]);                                 \
      aZ[rt] = MFMA16x16(a0, whh_z0, aZ[rt]);                                 \
      aZ[rt] = MFMA16x16(a1, whh_z1, aZ[rt]);                                 \
      aN[rt] = MFMA16x16(a0, whh_n0, aN[rt]);                                 \
      aN[rt] = MFMA16x16(a1, whh_n1, aN[rt]);                                 \
    }                                                                         \
    /* emb MFMAs, 1st half (consumes wb0_..wb3_) */                           \
    short8 ea_ = pack8cvt(e0, e1);                                            \
    acc[0] = MFMA16x16(ea_, wb0_, acc[0]);                                    \
    acc[1] = MFMA16x16(ea_, wb1_, acc[1]);                                    \
    acc[2] = MFMA16x16(ea_, wb2_, acc[2]);                                    \
    acc[3] = MFMA16x16(ea_, wb3_, acc[3]);                                    \
    /* 2nd half of Wc1 frags: latency hides under the gate VALU below */      \
    short8 wb4_ = *(const short8*)(wfrag + ((((S) * 8 + 4) * 64 + lane) * 8));\
    short8 wb5_ = *(const short8*)(wfrag + ((((S) * 8 + 5) * 64 + lane) * 8));\
    short8 wb6_ = *(const short8*)(wfrag + ((((S) * 8 + 6) * 64 + lane) * 8));\
    short8 wb7_ = *(const short8*)(wfrag + ((((S) * 8 + 7) * 64 + lane) * 8));\
    /* next emb fragment: consumed next step -> full-step latency cover */    \
    float4v f0_ = e0, f1_ = e1;                                               \
    if ((S) < 15) {                                                           \
      f0_ = *(const float4v*)(erow + ((S) + 1) * 32 + q * 8);                 \
      f1_ = *(const float4v*)(erow + ((S) + 1) * 32 + q * 8 + 4);             \
    }                                                                         \
    /* GRU gates (identical math to verified kernel) */                       \
    _Pragma("unroll")                                                         \
    for (int rt = 0; rt < 4; ++rt) {                                          \
      _Pragma("unroll")                                                       \
      for (int g = 0; g < 4; ++g) {                                           \
        int row = rt * 16 + q * 4 + g;                                        \
        float2 xv = *(const float2*)&xs[row][2 * (S)];                        \
        float rr = sig_poly(fmaf(wr0, xv.x, fmaf(wr1, xv.y, aR[rt][g])));     \
        float zz = sig_poly(fmaf(wz0, xv.x, fmaf(wz1, xv.y, aZ[rt][g])));     \
        float xn = fmaf(wn0, xv.x, fmaf(wn1, xv.y, bxn));                     \
        float nn = tanh_poly(fmaf(rr, aN[rt][g], xn));                        \
        float hh = fmaf(zz, hprev[rt][g] - nn, nn);                           \
        hprev[rt][g] = hh;                                                    \
        HW[row][dcol] = (short)f2bf(hh);                                      \
      }                                                                       \
    }                                                                         \
    /* emb MFMAs, 2nd half */                                                 \
    acc[4] = MFMA16x16(ea_, wb4_, acc[4]);                                    \
    acc[5] = MFMA16x16(ea_, wb5_, acc[5]);                                    \
    acc[6] = MFMA16x16(ea_, wb6_, acc[6]);                                    \
    acc[7] = MFMA16x16(ea_, wb7_, acc[7]);                                    \
    e0 = f0_; e1 = f1_;                                                       \
    __syncthreads();                                                          \
  } while (0)

#pragma unroll 1
  for (int s2 = 0; s2 < 8; ++s2) {
    FUSED_STEP(2 * s2, hb0, hb1);
    FUSED_STEP(2 * s2 + 1, hb1, hb0);
  }
  // h_last now in hb0 (step 15 wrote hb0; its barrier already executed).

  // ---- + h_last @ Wc2^T (row-split per wave), exact GELU, store ----
  {
    short8 ha0 = *(const short8*)&hb0[r0 + c][q * 8];
    short8 ha1 = *(const short8*)&hb0[r0 + c][32 + q * 8];
#pragma unroll
    for (int nt = 0; nt < 8; ++nt) {
      short8 b0 = *(const short8*)(wfrag + WC2_OFF + (((0 * 8 + nt) * 64 + lane) * 8));
      short8 b1 = *(const short8*)(wfrag + WC2_OFF + (((1 * 8 + nt) * 64 + lane) * 8));
      acc[nt] = MFMA16x16(ha0, b0, acc[nt]);
      acc[nt] = MFMA16x16(ha1, b1, acc[nt]);
    }
  }

  float* orow = out + (rowblk + r0 + q * 4) * 128;
#pragma unroll
  for (int g = 0; g < 4; ++g) {               // g outer: both 64B halves of each 128B line adjacent
#pragma unroll
    for (int nt = 0; nt < 8; ++nt) {
      float xv = acc[nt][g];
      float gl = 0.5f * xv * (1.0f + erff(xv * 0.70710678f));
      orow[(long)g * 128 + nt * 16 + c] = gl;
    }
  }
}

extern "C" void kernel_launch(void* const* d_in, const int* in_sizes, int n_in,
                              void* d_out, int out_size, void* d_ws, size_t ws_size,
                              hipStream_t stream) {
  (void)n_in; (void)out_size; (void)ws_size;
  const float* emb = (const float*)d_in[0];
  const float* cent = (const float*)d_in[1];
  const float* Wih = (const float*)d_in[2];
  const float* Whh = (const float*)d_in[3];
  const float* bih = (const float*)d_in[4];
  const float* bhh = (const float*)d_in[5];
  const float* Wt  = (const float*)d_in[6];
  const float* bt  = (const float*)d_in[7];
  const float* Wa  = (const float*)d_in[8];
  const float* ba  = (const float*)d_in[9];
  const float* Wf  = (const float*)d_in[10];
  const float* bfv = (const float*)d_in[11];
  float* out = (float*)d_out;

  short* wfrag = (short*)d_ws;
  float* bc = (float*)((char*)d_ws + BC_BYTE_OFF);

  const int B = in_sizes[0] / 512;       // 131072
  hipLaunchKernelGGL(tie_setup, dim3(337), dim3(256), 0, stream,
                     Whh, Wt, bt, Wa, ba, Wf, bfv, wfrag, bc);
  hipLaunchKernelGGL(tie_main, dim3(B / 64), dim3(256), 0, stream,
                     emb, cent, Wih, bih, bhh, wfrag, bc, out);
}

// Round 3
// 519.461 us; speedup vs baseline: 1.2805x; 1.2805x over previous
//
#include <hip/hip_runtime.h>

typedef __attribute__((ext_vector_type(8))) short short8;
typedef __attribute__((ext_vector_type(4))) short short4v;
typedef __attribute__((ext_vector_type(4))) float float4v;

// ws layout (shorts unless noted):
//   [0      , 65536) : Wc1 = Wf[:, :128] @ Wa   bf16, B-frag-major: ((kc*8+nt)*64+lane)*8+j
//   [65536  , 73728) : Wc2 = Wf[:, 128:] @ Wt   bf16, ((hf*8+nt)*64+lane)*8+j
//   [73728  , 86016) : Whh bf16 frags            ((nt2*2+hf)*64+lane)*8+j, col=nt2*16+c
//   byte 172032      : bc[128] f32 = bf + Wf[:, :128]@ba + Wf[:, 128:]@bt
#define WC2_OFF 65536
#define WHH_OFF 73728
#define BC_BYTE_OFF 172032

static __device__ __forceinline__ unsigned short f2bf(float f) {
  unsigned int u = __float_as_uint(f);
  u = (u + 0x7fffu + ((u >> 16) & 1u)) >> 16;   // RNE
  return (unsigned short)u;
}

static __device__ __forceinline__ short8 pack8cvt(float4v a, float4v b) {
  unsigned int u0, u1, u2, u3;
  asm("v_cvt_pk_bf16_f32 %0, %1, %2" : "=v"(u0) : "v"(a.x), "v"(a.y));
  asm("v_cvt_pk_bf16_f32 %0, %1, %2" : "=v"(u1) : "v"(a.z), "v"(a.w));
  asm("v_cvt_pk_bf16_f32 %0, %1, %2" : "=v"(u2) : "v"(b.x), "v"(b.y));
  asm("v_cvt_pk_bf16_f32 %0, %1, %2" : "=v"(u3) : "v"(b.z), "v"(b.w));
  union { unsigned int u[4]; short8 s; } r;
  r.u[0] = u0; r.u[1] = u1; r.u[2] = u2; r.u[3] = u3;
  return r.s;
}

// sigmoid(x) ~ 0.5 + x*(0.25 + s1*x^2 + s2*x^4) on [-2.4,2.4]; gate preacts are |x|<~0.8
static __device__ __forceinline__ float sig_poly(float x) {
  x = fminf(2.4f, fmaxf(-2.4f, x));
  float x2 = x * x;
  float t = fmaf(0.0010218f, x2, -0.0191312f);
  t = fmaf(t, x2, 0.25f);
  return fmaf(x, t, 0.5f);
}
// tanh(x) ~ x*(1 + c1*x^2 + c2*x^4) on [-1.2,1.2]
static __device__ __forceinline__ float tanh_poly(float x) {
  x = fminf(1.2f, fmaxf(-1.2f, x));
  float x2 = x * x;
  float t = fmaf(0.0654f, x2, -0.3061f);
  t = fmaf(t, x2, 1.0f);
  return x * t;
}

#define MFMA16x16(a, b, c) __builtin_amdgcn_mfma_f32_16x16x32_bf16((a), (b), (c), 0, 0, 0)

// ---------------- setup: fold the affine tail + pre-pack all MFMA B-fragments ----------------
__global__ __launch_bounds__(256) void tie_setup(
    const float* __restrict__ Whh,
    const float* __restrict__ Wt, const float* __restrict__ bt,
    const float* __restrict__ Wa, const float* __restrict__ ba,
    const float* __restrict__ Wf, const float* __restrict__ bfv,
    short* __restrict__ wfrag, float* __restrict__ bc)
{
  int gid = blockIdx.x * 256 + (int)threadIdx.x;
  if (gid < 65536) {                       // Wc1[n][k], n<128, k<512
    int n = gid >> 9, k = gid & 511;
    const float* wfr = Wf + (long)n * 256;
    const float* wac = Wa + k;
    float s = 0.f;
    for (int j = 0; j < 128; ++j) s = fmaf(wfr[j], wac[(long)j * 512], s);
    int nt = n >> 4, cc = n & 15, kc = k >> 5, qq = (k >> 3) & 3, jj = k & 7;
    wfrag[(((kc * 8 + nt) * 64 + (qq * 16 + cc)) * 8) + jj] = (short)f2bf(s);
  } else if (gid < 73728) {                // Wc2[n][k], n<128, k<64
    int i = gid - 65536;
    int n = i >> 6, k = i & 63;
    const float* wfr = Wf + (long)n * 256 + 128;
    const float* wtc = Wt + k;
    float s = 0.f;
    for (int j = 0; j < 128; ++j) s = fmaf(wfr[j], wtc[(long)j * 64], s);
    int nt = n >> 4, cc = n & 15, hf = k >> 5, qq = (k >> 3) & 3, jj = k & 7;
    wfrag[WC2_OFF + (((hf * 8 + nt) * 64 + (qq * 16 + cc)) * 8) + jj] = (short)f2bf(s);
  } else if (gid < 86016) {                // Whh bf16 frag pack (identity copy into frag layout)
    int i = gid - 73728;
    int jj = i & 7, lane = (i >> 3) & 63, hf = (i >> 9) & 1, nt2 = i >> 10;
    int cc = lane & 15, qq = lane >> 4;
    float v = Whh[(long)(nt2 * 16 + cc) * 64 + hf * 32 + qq * 8 + jj];
    wfrag[WHH_OFF + i] = (short)f2bf(v);
  } else if (gid < 86016 + 128) {          // bc
    int n = gid - 86016;
    const float* wfr = Wf + (long)n * 256;
    float s = bfv[n];
    for (int j = 0; j < 128; ++j) s = fmaf(wfr[j], ba[j], fmaf(wfr[128 + j], bt[j], s));
    bc[n] = s;
  }
}

// ---------------- main ----------------
// Block = 256 threads (4 waves), 64 rows/block.
// GRU is DIM-SPLIT: wave wv owns h-dims [wv*16, wv*16+16) for ALL 64 rows ->
// only 6 Whh frags (24 VGPR) + scalar gate consts per lane. h double-buffered in LDS,
// 1 barrier/step. Output phase is row-split (wave wv owns rows wv*16..+15), barrier-free,
// B-frags streamed pre-packed from L2, emb streamed with DEPTH-4 register prefetch
// (statically-named rolling buffers -> no spill, ~400+cyc of HBM latency cover).
__global__ __launch_bounds__(256, 4) void tie_main(
    const float* __restrict__ emb, const float* __restrict__ cent,
    const float* __restrict__ Wih, const float* __restrict__ bih,
    const float* __restrict__ bhh,
    const short* __restrict__ wfrag, const float* __restrict__ bc,
    float* __restrict__ out)
{
  __shared__ __align__(16) short hb0[64][72];   // h ping (+8 pad: stride 144B -> conflict-free frag reads)
  __shared__ __align__(16) short hb1[64][72];   // h pong
  __shared__ __align__(16) float xs[64][36];    // centroid history [row][2*step], +4 pad

  const int tid = (int)threadIdx.x;
  const int lane = tid & 63;
  const int wv = tid >> 6;
  const int c = lane & 15;
  const int q = lane >> 4;
  const int dcol = wv * 16 + c;                 // this lane's h-dim in the GRU
  const long rowblk = (long)blockIdx.x * 64;

  // ---- init: zero h ping, stage x into LDS ----
  {
    short8 z8 = {0, 0, 0, 0, 0, 0, 0, 0};
    short8* hp = (short8*)&hb0[0][0];
    for (int i = tid; i < 576; i += 256) hp[i] = z8;
    const float* cb = cent + rowblk * 32;
    int row = tid >> 2, col0 = (tid & 3) * 8;
    float4v v0 = *(const float4v*)(cb + tid * 8);
    float4v v1 = *(const float4v*)(cb + tid * 8 + 4);
    *(float4v*)&xs[row][col0] = v0;
    *(float4v*)&xs[row][col0 + 4] = v1;
  }

  // ---- per-lane scalar gate constants (dim = dcol) ----
  const int gr = dcol, gz = 64 + dcol, gn = 128 + dcol;
  const float accb_r = bih[gr] + bhh[gr];
  const float accb_z = bih[gz] + bhh[gz];
  const float accb_n = bhh[gn];                 // n-gate: r multiplies (hn + b_hh) only
  const float bxn = bih[gn];
  const float wr0 = Wih[2 * gr], wr1 = Wih[2 * gr + 1];
  const float wz0 = Wih[2 * gz], wz1 = Wih[2 * gz + 1];
  const float wn0 = Wih[2 * gn], wn1 = Wih[2 * gn + 1];

  // ---- Whh B-frags for this wave's 16 dims: 3 gates x 2 k-halves = 24 VGPR ----
  const short* whbase = wfrag + WHH_OFF;
  short8 whh_r0 = *(const short8*)(whbase + ((((0 * 4 + wv) * 2 + 0) * 64 + lane) * 8));
  short8 whh_r1 = *(const short8*)(whbase + ((((0 * 4 + wv) * 2 + 1) * 64 + lane) * 8));
  short8 whh_z0 = *(const short8*)(whbase + ((((1 * 4 + wv) * 2 + 0) * 64 + lane) * 8));
  short8 whh_z1 = *(const short8*)(whbase + ((((1 * 4 + wv) * 2 + 1) * 64 + lane) * 8));
  short8 whh_n0 = *(const short8*)(whbase + ((((2 * 4 + wv) * 2 + 0) * 64 + lane) * 8));
  short8 whh_n1 = *(const short8*)(whbase + ((((2 * 4 + wv) * 2 + 1) * 64 + lane) * 8));

  float hprev[4][4];
#pragma unroll
  for (int rt = 0; rt < 4; ++rt)
#pragma unroll
    for (int g = 0; g < 4; ++g) hprev[rt][g] = 0.0f;

  __syncthreads();

  // One GRU step: read prev h from HR, write new h to HW, barrier.
#define GRU_STEP(S, HR, HW)                                                   \
  do {                                                                        \
    float4v aR[4], aZ[4], aN[4];                                              \
    _Pragma("unroll")                                                         \
    for (int rt = 0; rt < 4; ++rt) {                                          \
      aR[rt] = (float4v){accb_r, accb_r, accb_r, accb_r};                     \
      aZ[rt] = (float4v){accb_z, accb_z, accb_z, accb_z};                     \
      aN[rt] = (float4v){accb_n, accb_n, accb_n, accb_n};                     \
    }                                                                         \
    _Pragma("unroll")                                                         \
    for (int rt = 0; rt < 4; ++rt) {                                          \
      short8 a0 = *(const short8*)&HR[rt * 16 + c][q * 8];                    \
      short8 a1 = *(const short8*)&HR[rt * 16 + c][32 + q * 8];               \
      aR[rt] = MFMA16x16(a0, whh_r0, aR[rt]);                                 \
      aR[rt] = MFMA16x16(a1, whh_r1, aR[rt]);                                 \
      aZ[rt] = MFMA16x16(a0, whh_z0, aZ[rt]);                                 \
      aZ[rt] = MFMA16x16(a1, whh_z1, aZ[rt]);                                 \
      aN[rt] = MFMA16x16(a0, whh_n0, aN[rt]);                                 \
      aN[rt] = MFMA16x16(a1, whh_n1, aN[rt]);                                 \
    }                                                                         \
    _Pragma("unroll")                                                         \
    for (int rt = 0; rt < 4; ++rt) {                                          \
      _Pragma("unroll")                                                       \
      for (int g = 0; g < 4; ++g) {                                           \
        int row = rt * 16 + q * 4 + g;                                        \
        float2 xv = *(const float2*)&xs[row][2 * (S)];                        \
        float rr = sig_poly(fmaf(wr0, xv.x, fmaf(wr1, xv.y, aR[rt][g])));     \
        float zz = sig_poly(fmaf(wz0, xv.x, fmaf(wz1, xv.y, aZ[rt][g])));     \
        float xn = fmaf(wn0, xv.x, fmaf(wn1, xv.y, bxn));                     \
        float nn = tanh_poly(fmaf(rr, aN[rt][g], xn));                        \
        float hh = fmaf(zz, hprev[rt][g] - nn, nn);                           \
        hprev[rt][g] = hh;                                                    \
        HW[row][dcol] = (short)f2bf(hh);                                      \
      }                                                                       \
    }                                                                         \
    __syncthreads();                                                          \
  } while (0)

#pragma unroll 1
  for (int s2 = 0; s2 < 8; ++s2) {
    GRU_STEP(2 * s2, hb0, hb1);
    GRU_STEP(2 * s2 + 1, hb1, hb0);
  }
  // h_last now in hb0 (step 15 wrote hb0; its barrier already executed).

  // ---- output: out = gelu(emb @ Wc1^T + h_last @ Wc2^T + bc), row-split per wave ----
  const int r0 = wv * 16;
  const float* erow = emb + (rowblk + r0 + c) * 512;   // emb A-frag row m = c

  // depth-4 emb prefetch: issue chunks 0..3 immediately (HBM latency ~900cy,
  // covered by the Wc2 section + 3 chunk-iterations of issue below)
  float4v eb0a = *(const float4v*)(erow + 0 * 32 + q * 8);
  float4v eb0b = *(const float4v*)(erow + 0 * 32 + q * 8 + 4);
  float4v eb1a = *(const float4v*)(erow + 1 * 32 + q * 8);
  float4v eb1b = *(const float4v*)(erow + 1 * 32 + q * 8 + 4);
  float4v eb2a = *(const float4v*)(erow + 2 * 32 + q * 8);
  float4v eb2b = *(const float4v*)(erow + 2 * 32 + q * 8 + 4);
  float4v eb3a = *(const float4v*)(erow + 3 * 32 + q * 8);
  float4v eb3b = *(const float4v*)(erow + 3 * 32 + q * 8 + 4);

  float4v acc[8];
#pragma unroll
  for (int nt = 0; nt < 8; ++nt) {
    float bv = bc[nt * 16 + c];
    acc[nt] = (float4v){bv, bv, bv, bv};
  }

  // h_last @ Wc2^T first: its L2 frag loads + 16 MFMAs overlap the emb prefetch
  {
    short8 ha0 = *(const short8*)&hb0[r0 + c][q * 8];
    short8 ha1 = *(const short8*)&hb0[r0 + c][32 + q * 8];
#pragma unroll
    for (int nt = 0; nt < 8; ++nt) {
      short8 b0 = *(const short8*)(wfrag + WC2_OFF + (((0 * 8 + nt) * 64 + lane) * 8));
      short8 b1 = *(const short8*)(wfrag + WC2_OFF + (((1 * 8 + nt) * 64 + lane) * 8));
      acc[nt] = MFMA16x16(ha0, b0, acc[nt]);
      acc[nt] = MFMA16x16(ha1, b1, acc[nt]);
    }
  }

  // One emb chunk: 8 wb frag loads (L2), pack, refill this slot from chunk KC+4, 8 MFMAs.
#define EMB_STEP(KC, EA0, EA1)                                                \
  do {                                                                        \
    const short* wbp_ = wfrag + (long)(KC) * 4096 + lane * 8;                 \
    short8 w0_ = *(const short8*)(wbp_);                                      \
    short8 w1_ = *(const short8*)(wbp_ + 512);                                \
    short8 w2_ = *(const short8*)(wbp_ + 1024);                               \
    short8 w3_ = *(const short8*)(wbp_ + 1536);                               \
    short8 w4_ = *(const short8*)(wbp_ + 2048);                               \
    short8 w5_ = *(const short8*)(wbp_ + 2560);                               \
    short8 w6_ = *(const short8*)(wbp_ + 3072);                               \
    short8 w7_ = *(const short8*)(wbp_ + 3584);                               \
    short8 ea_ = pack8cvt(EA0, EA1);                                          \
    if ((KC) < 12) {  /* WAR on EA regs: refill AFTER pack consumed them */   \
      EA0 = *(const float4v*)(erow + ((KC) + 4) * 32 + q * 8);                \
      EA1 = *(const float4v*)(erow + ((KC) + 4) * 32 + q * 8 + 4);            \
    }                                                                         \
    acc[0] = MFMA16x16(ea_, w0_, acc[0]);                                     \
    acc[1] = MFMA16x16(ea_, w1_, acc[1]);                                     \
    acc[2] = MFMA16x16(ea_, w2_, acc[2]);                                     \
    acc[3] = MFMA16x16(ea_, w3_, acc[3]);                                     \
    acc[4] = MFMA16x16(ea_, w4_, acc[4]);                                     \
    acc[5] = MFMA16x16(ea_, w5_, acc[5]);                                     \
    acc[6] = MFMA16x16(ea_, w6_, acc[6]);                                     \
    acc[7] = MFMA16x16(ea_, w7_, acc[7]);                                     \
  } while (0)

#pragma unroll 1
  for (int ko = 0; ko < 16; ko += 4) {
    EMB_STEP(ko + 0, eb0a, eb0b);
    EMB_STEP(ko + 1, eb1a, eb1b);
    EMB_STEP(ko + 2, eb2a, eb2b);
    EMB_STEP(ko + 3, eb3a, eb3b);
  }

  float* orow = out + (rowblk + r0 + q * 4) * 128;
#pragma unroll
  for (int g = 0; g < 4; ++g) {               // g outer: both 64B halves of each 128B line adjacent
#pragma unroll
    for (int nt = 0; nt < 8; ++nt) {
      float xv = acc[nt][g];
      float gl = 0.5f * xv * (1.0f + erff(xv * 0.70710678f));
      orow[(long)g * 128 + nt * 16 + c] = gl;
    }
  }
}

extern "C" void kernel_launch(void* const* d_in, const int* in_sizes, int n_in,
                              void* d_out, int out_size, void* d_ws, size_t ws_size,
                              hipStream_t stream) {
  (void)n_in; (void)out_size; (void)ws_size;
  const float* emb = (const float*)d_in[0];
  const float* cent = (const float*)d_in[1];
  const float* Wih = (const float*)d_in[2];
  const float* Whh = (const float*)d_in[3];
  const float* bih = (const float*)d_in[4];
  const float* bhh = (const float*)d_in[5];
  const float* Wt  = (const float*)d_in[6];
  const float* bt  = (const float*)d_in[7];
  const float* Wa  = (const float*)d_in[8];
  const float* ba  = (const float*)d_in[9];
  const float* Wf  = (const float*)d_in[10];
  const float* bfv = (const float*)d_in[11];
  float* out = (float*)d_out;

  short* wfrag = (short*)d_ws;
  float* bc = (float*)((char*)d_ws + BC_BYTE_OFF);

  const int B = in_sizes[0] / 512;       // 131072
  hipLaunchKernelGGL(tie_setup, dim3(337), dim3(256), 0, stream,
                     Whh, Wt, bt, Wa, ba, Wf, bfv, wfrag, bc);
  hipLaunchKernelGGL(tie_main, dim3(B / 64), dim3(256), 0, stream,
                     emb, cent, Wih, bih, bhh, wfrag, bc, out);
}